// Round 9
// baseline (4586.575 us; speedup 1.0000x reference)
//
#include <hip/hip_runtime.h>
#include <hip/hip_bf16.h>

#define T_STEPS 512
#define BATCH   256
#define HID     100
#define GATES   400   // 4*H
#define BT      (BATCH * T_STEPS)

__device__ __forceinline__ float sigm_f(float x) {
    return 1.f / (1.f + __expf(-x));
}

__device__ __forceinline__ float tanh_f(float x) {
    float ax = fabsf(x);
    float t  = __expf(-2.f * ax);
    float r  = (1.f - t) / (1.f + t);
    return copysignf(r, x);
}

// ---------------------------------------------------------------------------
// xg GEMM v5: A streamed DIRECTLY from global (16 lanes share each row
// address -> L1 broadcast; the 4 same-XCD col-tile blocks share A k-slices
// in L2 -- round-8 FETCH proved this works). W double-buffered in LDS
// (2x10.2 KB). 8x8 microtile, BM=128, BN=128 (400 padded to 512), BK=20.
// kk-loop unroll 2 bounds in-flight a4 registers (round-5 lesson).
// XCD swizzle: the 4 col-tiles of one row-tile share bid%8 -> same XCD L2.
// NO min-waves hint (rounds 1-3: caps below the live set spill acc).
// ---------------------------------------------------------------------------
template <int K, bool GATHER>
__global__ __launch_bounds__(256) void xg_gemm(
    const float* __restrict__ A, const int* __restrict__ idx,
    const float* __restrict__ W, const float* __restrict__ b1,
    const float* __restrict__ b2, float* __restrict__ out)
{
    __shared__ float Bs[2][128][20];

    const int bid   = blockIdx.x;
    const int xcd   = bid & 7;
    const int rest  = bid >> 3;
    const int ct    = rest & 3;
    const int rgrp  = rest >> 2;
    const int row0  = (rgrp * 8 + xcd) * 128;
    const int col0  = ct * 128;

    const int tid  = threadIdx.x;
    const int tx   = tid & 15;
    const int ty   = tid >> 4;

    // per-thread A row pointers (8 rows: ty + 16*r)
    const float* arow[8];
#pragma unroll
    for (int r = 0; r < 8; ++r) {
        int row = row0 + ty + 16 * r;
        int src = GATHER ? idx[row] : row;
        arow[r] = A + (size_t)src * K;
    }

    // stage W k-tile 0 into buffer 0
    for (int e = tid; e < 640; e += 256) {
        int r = e / 5, kq = e % 5;
        int wrow = col0 + r;
        float4 v = make_float4(0.f, 0.f, 0.f, 0.f);
        if (wrow < GATES)
            v = *(const float4*)(W + (size_t)wrow * K + kq * 4);
        *(float4*)(&Bs[0][r][kq * 4]) = v;
    }

    float acc[8][8];
#pragma unroll
    for (int r = 0; r < 8; ++r)
#pragma unroll
        for (int j = 0; j < 8; ++j) acc[r][j] = 0.f;

    int cur = 0;
#pragma unroll 1
    for (int k0 = 0; k0 < K; k0 += 20) {
        __syncthreads();   // Bs[cur] ready; Bs[cur^1] free

        // stage next W k-tile into the other buffer (overlaps compute)
        if (k0 + 20 < K) {
            for (int e = tid; e < 640; e += 256) {
                int r = e / 5, kq = e % 5;
                int wrow = col0 + r;
                float4 v = make_float4(0.f, 0.f, 0.f, 0.f);
                if (wrow < GATES)
                    v = *(const float4*)(W + (size_t)wrow * K + (k0 + 20) + kq * 4);
                *(float4*)(&Bs[cur ^ 1][r][kq * 4]) = v;
            }
        }

#pragma unroll 2
        for (int kk = 0; kk < 20; kk += 4) {
            float4 a4[8];
#pragma unroll
            for (int r = 0; r < 8; ++r)
                a4[r] = *(const float4*)(arow[r] + k0 + kk);
#pragma unroll
            for (int j = 0; j < 8; ++j) {
                float4 b4 = *(const float4*)(&Bs[cur][tx + 16 * j][kk]);
#pragma unroll
                for (int r = 0; r < 8; ++r) {
                    acc[r][j] += a4[r].x * b4.x + a4[r].y * b4.y +
                                 a4[r].z * b4.z + a4[r].w * b4.w;
                }
            }
        }
        cur ^= 1;
    }

    // epilogue: bias + guarded store
#pragma unroll
    for (int r = 0; r < 8; ++r) {
        int row = row0 + ty + 16 * r;
#pragma unroll
        for (int j = 0; j < 8; ++j) {
            int col = col0 + tx + 16 * j;
            if (col < GATES)
                out[(size_t)row * GATES + col] = acc[r][j] + b1[col] + b2[col];
        }
    }
}

// ---------------------------------------------------------------------------
// Recurrent scan v5: TWO batches per block (serial chain was the wall at
// ~1970 cyc/step; two independent chains share one barrier and the same
// w4 registers). Thread 4j+gt: hidden j, k-quarter gt of all 4 gate rows.
// Per step per batch: 7 broadcast ds_read_b128, quad butterfly reduce,
// activation exchange via 3 shfl, redundant c/h in all 4 lanes.
// xg staged in 32-step chunks for both batches (102.4 KB LDS, 1 block/CU).
// ---------------------------------------------------------------------------
__global__ __launch_bounds__(448) void lstm_recur(
    const float* __restrict__ xg,    // [B, T, 400]
    const float* __restrict__ w_hh,  // [400, 100]
    const int*   __restrict__ lengths,
    float* __restrict__ hs)          // [B, T, 100]
{
    const int bp  = blockIdx.x;
    const int b0  = bp * 2, b1 = bp * 2 + 1;
    const int tid = threadIdx.x;
    const bool active = (tid < 400);
    const int j    = tid >> 2;
    const int gt   = tid & 3;

    __shared__ float xg_s[2][32 * GATES];  // 102.4 KB
    __shared__ float h_s[2][2][112];       // [batch][parity][4 padded segs]

    float w4[4][28];
    if (active) {
#pragma unroll
        for (int g = 0; g < 4; ++g) {
            const float* wr = w_hh + (size_t)(g * HID + j) * HID + gt * 25;
#pragma unroll
            for (int i = 0; i < 28; ++i)
                w4[g][i] = (i < 25) ? wr[i] : 0.f;
        }
    }
    // zero h buffers (2 batches x 2 parities x 112 = 448 floats)
    ((float*)h_s)[tid] = 0.f;

    float cA = 0.f, hA = 0.f, cB = 0.f, hB = 0.f;
    const int lenA = lengths[b0];
    const int lenB = lengths[b1];
    const float* xgb0 = xg + (size_t)b0 * T_STEPS * GATES;
    const float* xgb1 = xg + (size_t)b1 * T_STEPS * GATES;
    float*       hsb0 = hs + (size_t)b0 * T_STEPS * HID;
    float*       hsb1 = hs + (size_t)b1 * T_STEPS * HID;

    const bool is0 = (gt == 0), is1 = (gt == 1), is2 = (gt == 2);
    const int  hoff = gt * 28;
    const int  seg  = (j / 25) * 28 + (j % 25);
    const int  xcol = gt * HID + j;

    for (int t = 0; t < T_STEPS; ++t) {
        if ((t & 31) == 0) {
            const float4* s0 = (const float4*)(xgb0 + (size_t)t * GATES);
            const float4* s1 = (const float4*)(xgb1 + (size_t)t * GATES);
            float4* d0 = (float4*)xg_s[0];
            float4* d1 = (float4*)xg_s[1];
            for (int i = tid; i < 3200; i += 448) {
                d0[i] = s0[i];
                d1[i] = s1[i];
            }
            __syncthreads();
        }

        float a0 = 0.f, a1 = 0.f, a2 = 0.f, a3 = 0.f;
        float e0 = 0.f, e1 = 0.f, e2 = 0.f, e3 = 0.f;
        if (active) {
            const float* ha = h_s[0][t & 1] + hoff;
            const float* hb = h_s[1][t & 1] + hoff;
#pragma unroll
            for (int i = 0; i < 28; i += 4) {
                float4 h4 = *(const float4*)(ha + i);
                a0 += w4[0][i] * h4.x + w4[0][i+1] * h4.y + w4[0][i+2] * h4.z + w4[0][i+3] * h4.w;
                a1 += w4[1][i] * h4.x + w4[1][i+1] * h4.y + w4[1][i+2] * h4.z + w4[1][i+3] * h4.w;
                a2 += w4[2][i] * h4.x + w4[2][i+1] * h4.y + w4[2][i+2] * h4.z + w4[2][i+3] * h4.w;
                a3 += w4[3][i] * h4.x + w4[3][i+1] * h4.y + w4[3][i+2] * h4.z + w4[3][i+3] * h4.w;
                float4 g4 = *(const float4*)(hb + i);
                e0 += w4[0][i] * g4.x + w4[0][i+1] * g4.y + w4[0][i+2] * g4.z + w4[0][i+3] * g4.w;
                e1 += w4[1][i] * g4.x + w4[1][i+1] * g4.y + w4[1][i+2] * g4.z + w4[1][i+3] * g4.w;
                e2 += w4[2][i] * g4.x + w4[2][i+1] * g4.y + w4[2][i+2] * g4.z + w4[2][i+3] * g4.w;
                e3 += w4[3][i] * g4.x + w4[3][i+1] * g4.y + w4[3][i+2] * g4.z + w4[3][i+3] * g4.w;
            }
        }
        // quad butterfly all-reduce
        a0 += __shfl_xor(a0, 1); a0 += __shfl_xor(a0, 2);
        a1 += __shfl_xor(a1, 1); a1 += __shfl_xor(a1, 2);
        a2 += __shfl_xor(a2, 1); a2 += __shfl_xor(a2, 2);
        a3 += __shfl_xor(a3, 1); a3 += __shfl_xor(a3, 2);
        e0 += __shfl_xor(e0, 1); e0 += __shfl_xor(e0, 2);
        e1 += __shfl_xor(e1, 1); e1 += __shfl_xor(e1, 2);
        e2 += __shfl_xor(e2, 1); e2 += __shfl_xor(e2, 2);
        e3 += __shfl_xor(e3, 1); e3 += __shfl_xor(e3, 2);

        float sA = is0 ? a0 : is1 ? a1 : is2 ? a2 : a3;
        float sB = is0 ? e0 : is1 ? e1 : is2 ? e2 : e3;
        float preA = 0.f, preB = 0.f;
        if (active) {
            const float* xrow = &xg_s[0][(t & 31) * GATES + xcol];
            preA = sA + xrow[0];
            preB = sB + (&xg_s[1][0] - &xg_s[0][0]) == 0 ? 0.f : sB + xg_s[1][(t & 31) * GATES + xcol];
        }
        // (the line above must not confuse the compiler -- recompute simply)
        if (active) {
            preA = sA + xg_s[0][(t & 31) * GATES + xcol];
            preB = sB + xg_s[1][(t & 31) * GATES + xcol];
        }

        float pA0 = is2 ? tanh_f(preA) : sigm_f(preA);
        float pB0 = is2 ? tanh_f(preB) : sigm_f(preB);
        float pA1 = __shfl_xor(pA0, 1);
        float pA2 = __shfl_xor(pA0, 2);
        float pA3 = __shfl_xor(pA1, 2);
        float pB1 = __shfl_xor(pB0, 1);
        float pB2 = __shfl_xor(pB0, 2);
        float pB3 = __shfl_xor(pB1, 2);

        float ivA = is0 ? pA0 : is1 ? pA1 : is2 ? pA2 : pA3;
        float fvA = is0 ? pA1 : is1 ? pA0 : is2 ? pA3 : pA2;
        float gvA = is0 ? pA2 : is1 ? pA3 : is2 ? pA0 : pA1;
        float ovA = is0 ? pA3 : is1 ? pA2 : is2 ? pA1 : pA0;
        float ivB = is0 ? pB0 : is1 ? pB1 : is2 ? pB2 : pB3;
        float fvB = is0 ? pB1 : is1 ? pB0 : is2 ? pB3 : pB2;
        float gvB = is0 ? pB2 : is1 ? pB3 : is2 ? pB0 : pB1;
        float ovB = is0 ? pB3 : is1 ? pB2 : is2 ? pB1 : pB0;

        float cnA = fvA * cA + ivA * gvA;
        float hnA = ovA * tanh_f(cnA);
        float cnB = fvB * cB + ivB * gvB;
        float hnB = ovB * tanh_f(cnB);
        bool mA = (t < lenA), mB = (t < lenB);
        cA = mA ? cnA : cA;  hA = mA ? hnA : hA;
        cB = mB ? cnB : cB;  hB = mB ? hnB : hB;

        if (active && gt == 0) {
            h_s[0][(t & 1) ^ 1][seg] = hA;
            h_s[1][(t & 1) ^ 1][seg] = hB;
            hsb0[(size_t)t * HID + j] = hA;
            hsb1[(size_t)t * HID + j] = hB;
        }
        __syncthreads();
    }
}

// ---------------------------------------------------------------------------
// Final linear head
// ---------------------------------------------------------------------------
__global__ __launch_bounds__(64) void fc_kernel(
    const float* __restrict__ hs, const float* __restrict__ w_fc,
    const float* __restrict__ b_fc, float* __restrict__ out)
{
    int tid = blockIdx.x * 64 + threadIdx.x;
    if (tid >= BATCH * 3) return;
    int b = tid / 3, o = tid % 3;
    const float* h = hs + ((size_t)b * T_STEPS + (T_STEPS - 1)) * HID;
    float acc = b_fc[o];
    for (int j = 0; j < HID; ++j) acc += h[j] * w_fc[o * HID + j];
    out[b * 3 + o] = acc;
}

extern "C" void kernel_launch(void* const* d_in, const int* in_sizes, int n_in,
                              void* d_out, int out_size, void* d_ws, size_t ws_size,
                              hipStream_t stream)
{
    const int*   x       = (const int*)  d_in[0];
    const int*   lengths = (const int*)  d_in[1];
    const float* emb     = (const float*)d_in[2];
    const float* w_ih0   = (const float*)d_in[3];
    const float* w_hh0   = (const float*)d_in[4];
    const float* b_ih0   = (const float*)d_in[5];
    const float* b_hh0   = (const float*)d_in[6];
    const float* w_ih1   = (const float*)d_in[7];
    const float* w_hh1   = (const float*)d_in[8];
    const float* b_ih1   = (const float*)d_in[9];
    const float* b_hh1   = (const float*)d_in[10];
    const float* w_ih2   = (const float*)d_in[11];
    const float* w_hh2   = (const float*)d_in[12];
    const float* b_ih2   = (const float*)d_in[13];
    const float* b_hh2   = (const float*)d_in[14];
    const float* w_fc    = (const float*)d_in[15];
    const float* b_fc    = (const float*)d_in[16];
    float* out = (float*)d_out;

    float* xg = (float*)d_ws;                  // [BT, 400]  ~210 MB
    float* hs = xg + (size_t)BT * GATES;       // [BT, 100]  ~52 MB

    const int nblk = (BT / 128) * 4;   // 4096, XCD-swizzled inside kernel

    // Layer 0: embedding gather fused into A-stage, K=300
    xg_gemm<300, true><<<nblk, 256, 0, stream>>>(emb, x, w_ih0, b_ih0, b_hh0, xg);
    lstm_recur<<<BATCH / 2, 448, 0, stream>>>(xg, w_hh0, lengths, hs);

    // Layer 1
    xg_gemm<100, false><<<nblk, 256, 0, stream>>>(hs, nullptr, w_ih1, b_ih1, b_hh1, xg);
    lstm_recur<<<BATCH / 2, 448, 0, stream>>>(xg, w_hh1, lengths, hs);

    // Layer 2
    xg_gemm<100, false><<<nblk, 256, 0, stream>>>(hs, nullptr, w_ih2, b_ih2, b_hh2, xg);
    lstm_recur<<<BATCH / 2, 448, 0, stream>>>(xg, w_hh2, lengths, hs);

    // Head
    fc_kernel<<<(BATCH * 3 + 63) / 64, 64, 0, stream>>>(hs, w_fc, b_fc, out);
}

// Round 10
// 2736.472 us; speedup vs baseline: 1.6761x; 1.6761x over previous
//
#include <hip/hip_runtime.h>
#include <hip/hip_bf16.h>

#define T_STEPS 512
#define BATCH   256
#define HID     100
#define GATES   400   // 4*H
#define BT      (BATCH * T_STEPS)

__device__ __forceinline__ float sigm_f(float x) {
    return 1.f / (1.f + __expf(-x));
}

__device__ __forceinline__ float tanh_f(float x) {
    float ax = fabsf(x);
    float t  = __expf(-2.f * ax);
    float r  = (1.f - t) / (1.f + t);
    return copysignf(r, x);
}

// ---------------------------------------------------------------------------
// xg GEMM v6 = round-7 double-buffered LDS staging (keeps loads in flight
// across the k-loop barrier; VALUBusy 56%) + round-8 XCD swizzle (the 4
// col-tiles of one row-tile share bid%8 -> same XCD L2; FETCH 321->86 MB).
// BM=128, BN=128 (400 padded), BK=20, 8x8 microtile, strided ownership.
// NO min-waves hint (rounds 1-3: any cap below the live set spills acc).
// ---------------------------------------------------------------------------
template <int K, bool GATHER>
__global__ __launch_bounds__(256) void xg_gemm(
    const float* __restrict__ A, const int* __restrict__ idx,
    const float* __restrict__ W, const float* __restrict__ b1,
    const float* __restrict__ b2, float* __restrict__ out)
{
    __shared__ float As[2][128][20];
    __shared__ float Bs[2][128][20];
    __shared__ int   idx_s[128];

    // bid = xcd + 8*(col_tile + 4*row_group); row_tile = row_group*8 + xcd
    const int bid   = blockIdx.x;
    const int xcd   = bid & 7;
    const int rest  = bid >> 3;
    const int ct    = rest & 3;
    const int rgrp  = rest >> 2;
    const int row0  = (rgrp * 8 + xcd) * 128;
    const int col0  = ct * 128;

    const int tid  = threadIdx.x;
    const int tx   = tid & 15;
    const int ty   = tid >> 4;

    if (GATHER) {
        if (tid < 128) idx_s[tid] = idx[row0 + tid];
        __syncthreads();
    }

    // initial stage: k-tile 0 into buffer 0
    for (int e = tid; e < 640; e += 256) {
        int r = e / 5, kq = e % 5;
        int src = GATHER ? idx_s[r] : (row0 + r);
        *(float4*)(&As[0][r][kq * 4]) =
            *(const float4*)(A + (size_t)src * K + kq * 4);
    }
    for (int e = tid; e < 640; e += 256) {
        int r = e / 5, kq = e % 5;
        int wrow = col0 + r;
        float4 v = make_float4(0.f, 0.f, 0.f, 0.f);
        if (wrow < GATES)
            v = *(const float4*)(W + (size_t)wrow * K + kq * 4);
        *(float4*)(&Bs[0][r][kq * 4]) = v;
    }

    float acc[8][8];
#pragma unroll
    for (int r = 0; r < 8; ++r)
#pragma unroll
        for (int j = 0; j < 8; ++j) acc[r][j] = 0.f;

    int cur = 0;
#pragma unroll 1
    for (int k0 = 0; k0 < K; k0 += 20) {
        __syncthreads();   // buf[cur] staged; buf[cur^1] free

        const int kn = k0 + 20;
        if (kn < K) {
            for (int e = tid; e < 640; e += 256) {
                int r = e / 5, kq = e % 5;
                int src = GATHER ? idx_s[r] : (row0 + r);
                *(float4*)(&As[cur ^ 1][r][kq * 4]) =
                    *(const float4*)(A + (size_t)src * K + kn + kq * 4);
            }
            for (int e = tid; e < 640; e += 256) {
                int r = e / 5, kq = e % 5;
                int wrow = col0 + r;
                float4 v = make_float4(0.f, 0.f, 0.f, 0.f);
                if (wrow < GATES)
                    v = *(const float4*)(W + (size_t)wrow * K + kn + kq * 4);
                *(float4*)(&Bs[cur ^ 1][r][kq * 4]) = v;
            }
        }

#pragma unroll
        for (int kk = 0; kk < 20; kk += 4) {
            float4 a4[8];
#pragma unroll
            for (int r = 0; r < 8; ++r)
                a4[r] = *(const float4*)(&As[cur][ty + 16 * r][kk]);
#pragma unroll
            for (int j = 0; j < 8; ++j) {
                float4 b4 = *(const float4*)(&Bs[cur][tx + 16 * j][kk]);
#pragma unroll
                for (int r = 0; r < 8; ++r) {
                    acc[r][j] += a4[r].x * b4.x + a4[r].y * b4.y +
                                 a4[r].z * b4.z + a4[r].w * b4.w;
                }
            }
        }
        cur ^= 1;
    }

#pragma unroll
    for (int r = 0; r < 8; ++r) {
        int row = row0 + ty + 16 * r;
#pragma unroll
        for (int j = 0; j < 8; ++j) {
            int col = col0 + tx + 16 * j;
            if (col < GATES)
                out[(size_t)row * GATES + col] = acc[r][j] + b1[col] + b2[col];
        }
    }
}

// ---------------------------------------------------------------------------
// Recurrent scan v6 (k-split quads, NO per-step global traffic):
//   thread 4j+gt: hidden j, quad-lane gt owns k-quarter of all 4 gate rows
//   (w4[4][28] in VGPRs). Per step: 7 broadcast ds_read_b128, 112 FMA,
//   quad butterfly reduce, 3-shfl activation exchange, redundant c/h.
//   KEY FIX vs rounds 6-9: h output goes to LDS h_hist and is flushed to
//   global once per 32-step chunk -- the per-step __syncthreads no longer
//   drains an HBM write (vmcnt(0) was costing 300-900 cyc on EVERY step).
//   WRITE_ALL=false (last layer): only the final h is written (fc needs
//   only hs[b, T-1, :]).
// ---------------------------------------------------------------------------
template <bool WRITE_ALL>
__global__ __launch_bounds__(448) void lstm_recur(
    const float* __restrict__ xg,    // [B, T, 400]
    const float* __restrict__ w_hh,  // [400, 100]
    const int*   __restrict__ lengths,
    float* __restrict__ hs)          // [B, T, 100]
{
    const int b   = blockIdx.x;
    const int tid = threadIdx.x;
    const bool active = (tid < 400);
    const int j    = tid >> 2;
    const int gt   = tid & 3;

    __shared__ float xg_s[32 * GATES];    // 51.2 KB chunk of xg
    __shared__ float h_s[2][112];         // padded 4 x 28 segments, dbuf
    __shared__ float h_hist[32 * HID];    // 12.8 KB chunk of h outputs

    float w4[4][28];
    if (active) {
#pragma unroll
        for (int g = 0; g < 4; ++g) {
            const float* wr = w_hh + (size_t)(g * HID + j) * HID + gt * 25;
#pragma unroll
            for (int i = 0; i < 28; ++i)
                w4[g][i] = (i < 25) ? wr[i] : 0.f;
        }
    }
    for (int i = tid; i < 224; i += 448) ((float*)h_s)[i] = 0.f;

    float c_reg = 0.f, h_reg = 0.f;
    const int len = lengths[b];
    const float* xgb = xg + (size_t)b * T_STEPS * GATES;
    float*       hsb = hs + (size_t)b * T_STEPS * HID;

    const bool is0 = (gt == 0), is1 = (gt == 1), is2 = (gt == 2);
    const int  hoff = gt * 28;
    const int  seg  = (j / 25) * 28 + (j % 25);
    const int  xcol = gt * HID + j;

    for (int t = 0; t < T_STEPS; ++t) {
        if ((t & 31) == 0) {
            // flush previous chunk's h history (coalesced, once per 32 steps)
            if (WRITE_ALL && t > 0) {
                const float4* s = (const float4*)h_hist;
                float4*       d = (float4*)(hsb + (size_t)(t - 32) * HID);
                for (int i = tid; i < 800; i += 448) d[i] = s[i];
            }
            // stage next xg chunk
            const float4* src = (const float4*)(xgb + (size_t)t * GATES);
            float4*       dst = (float4*)xg_s;
            for (int i = tid; i < 3200; i += 448) dst[i] = src[i];
            __syncthreads();   // drains the chunk's vmem + LDS once
        }

        float s0 = 0.f, s1 = 0.f, s2 = 0.f, s3 = 0.f;
        if (active) {
            const float* hb = h_s[t & 1] + hoff;
#pragma unroll
            for (int i = 0; i < 28; i += 4) {
                float4 h4 = *(const float4*)(hb + i);
                s0 += w4[0][i] * h4.x + w4[0][i+1] * h4.y +
                      w4[0][i+2] * h4.z + w4[0][i+3] * h4.w;
                s1 += w4[1][i] * h4.x + w4[1][i+1] * h4.y +
                      w4[1][i+2] * h4.z + w4[1][i+3] * h4.w;
                s2 += w4[2][i] * h4.x + w4[2][i+1] * h4.y +
                      w4[2][i+2] * h4.z + w4[2][i+3] * h4.w;
                s3 += w4[3][i] * h4.x + w4[3][i+1] * h4.y +
                      w4[3][i+2] * h4.z + w4[3][i+3] * h4.w;
            }
        }
        // quad butterfly all-reduce
        s0 += __shfl_xor(s0, 1); s0 += __shfl_xor(s0, 2);
        s1 += __shfl_xor(s1, 1); s1 += __shfl_xor(s1, 2);
        s2 += __shfl_xor(s2, 1); s2 += __shfl_xor(s2, 2);
        s3 += __shfl_xor(s3, 1); s3 += __shfl_xor(s3, 2);

        float sg = is0 ? s0 : is1 ? s1 : is2 ? s2 : s3;
        float pre = 0.f;
        if (active)
            pre = sg + xg_s[(t & 31) * GATES + xcol];

        float p0 = is2 ? tanh_f(pre) : sigm_f(pre);
        float p1 = __shfl_xor(p0, 1);
        float p2 = __shfl_xor(p0, 2);
        float p3 = __shfl_xor(p1, 2);
        float iv = is0 ? p0 : is1 ? p1 : is2 ? p2 : p3;
        float fv = is0 ? p1 : is1 ? p0 : is2 ? p3 : p2;
        float gv = is0 ? p2 : is1 ? p3 : is2 ? p0 : p1;
        float ov = is0 ? p3 : is1 ? p2 : is2 ? p1 : p0;

        float c_new = fv * c_reg + iv * gv;
        float h_new = ov * tanh_f(c_new);
        bool  m     = (t < len);
        c_reg = m ? c_new : c_reg;
        h_reg = m ? h_new : h_reg;

        if (active && gt == 0) {
            h_s[(t & 1) ^ 1][seg] = h_reg;
            if (WRITE_ALL) h_hist[(t & 31) * HID + j] = h_reg;
        }
        __syncthreads();   // LDS-only drain in steady state (fast)
    }

    if (WRITE_ALL) {
        // flush final chunk
        const float4* s = (const float4*)h_hist;
        float4*       d = (float4*)(hsb + (size_t)(T_STEPS - 32) * HID);
        for (int i = tid; i < 800; i += 448) d[i] = s[i];
    } else {
        // last layer: fc reads only hs[b, T-1, :]
        if (active && gt == 0)
            hsb[(size_t)(T_STEPS - 1) * HID + j] = h_reg;
    }
}

// ---------------------------------------------------------------------------
// Final linear head
// ---------------------------------------------------------------------------
__global__ __launch_bounds__(64) void fc_kernel(
    const float* __restrict__ hs, const float* __restrict__ w_fc,
    const float* __restrict__ b_fc, float* __restrict__ out)
{
    int tid = blockIdx.x * 64 + threadIdx.x;
    if (tid >= BATCH * 3) return;
    int b = tid / 3, o = tid % 3;
    const float* h = hs + ((size_t)b * T_STEPS + (T_STEPS - 1)) * HID;
    float acc = b_fc[o];
    for (int j = 0; j < HID; ++j) acc += h[j] * w_fc[o * HID + j];
    out[b * 3 + o] = acc;
}

extern "C" void kernel_launch(void* const* d_in, const int* in_sizes, int n_in,
                              void* d_out, int out_size, void* d_ws, size_t ws_size,
                              hipStream_t stream)
{
    const int*   x       = (const int*)  d_in[0];
    const int*   lengths = (const int*)  d_in[1];
    const float* emb     = (const float*)d_in[2];
    const float* w_ih0   = (const float*)d_in[3];
    const float* w_hh0   = (const float*)d_in[4];
    const float* b_ih0   = (const float*)d_in[5];
    const float* b_hh0   = (const float*)d_in[6];
    const float* w_ih1   = (const float*)d_in[7];
    const float* w_hh1   = (const float*)d_in[8];
    const float* b_ih1   = (const float*)d_in[9];
    const float* b_hh1   = (const float*)d_in[10];
    const float* w_ih2   = (const float*)d_in[11];
    const float* w_hh2   = (const float*)d_in[12];
    const float* b_ih2   = (const float*)d_in[13];
    const float* b_hh2   = (const float*)d_in[14];
    const float* w_fc    = (const float*)d_in[15];
    const float* b_fc    = (const float*)d_in[16];
    float* out = (float*)d_out;

    float* xg = (float*)d_ws;                  // [BT, 400]  ~210 MB
    float* hs = xg + (size_t)BT * GATES;       // [BT, 100]  ~52 MB

    const int nblk = (BT / 128) * 4;   // 4096, XCD-swizzled inside kernel

    // Layer 0: embedding gather fused into A-stage, K=300
    xg_gemm<300, true><<<nblk, 256, 0, stream>>>(emb, x, w_ih0, b_ih0, b_hh0, xg);
    lstm_recur<true><<<BATCH, 448, 0, stream>>>(xg, w_hh0, lengths, hs);

    // Layer 1
    xg_gemm<100, false><<<nblk, 256, 0, stream>>>(hs, nullptr, w_ih1, b_ih1, b_hh1, xg);
    lstm_recur<true><<<BATCH, 448, 0, stream>>>(xg, w_hh1, lengths, hs);

    // Layer 2
    xg_gemm<100, false><<<nblk, 256, 0, stream>>>(hs, nullptr, w_ih2, b_ih2, b_hh2, xg);
    lstm_recur<false><<<BATCH, 448, 0, stream>>>(xg, w_hh2, lengths, hs);

    // Head
    fc_kernel<<<(BATCH * 3 + 63) / 64, 64, 0, stream>>>(hs, w_fc, b_fc, out);
}